// Round 2
// baseline (698.384 us; speedup 1.0000x reference)
//
#include <hip/hip_runtime.h>
#include <cstdint>
#include <cstddef>

// Problem constants
#define TS     4
#define BNROWS 16384   // B*N = 32*512
#define DIMN   512
#define CIN    1024    // 2*DIM

typedef __attribute__((ext_vector_type(8))) short short8;   // 8 bf16
typedef __attribute__((ext_vector_type(4))) float f32x4;

__device__ __forceinline__ uint16_t f2bf(float f) {
    union { float f; uint32_t u; } x; x.f = f;
    return (uint16_t)((x.u + 0x7FFFu + ((x.u >> 16) & 1u)) >> 16);  // RNE
}
__device__ __forceinline__ float bf2f(uint16_t h) {
    union { uint32_t u; float f; } x; x.u = ((uint32_t)h) << 16;
    return x.f;
}

// ---------------- Kernel 0: split W (fp32) into bf16 hi/mid ----------------
__global__ __launch_bounds__(256) void k_wsplit(const float* __restrict__ W,
        uint16_t* __restrict__ Wh, uint16_t* __restrict__ Wm) {
    int i = (blockIdx.x * 256 + threadIdx.x) * 4;
    float4 w4 = *(const float4*)(W + i);
    float wv[4] = {w4.x, w4.y, w4.z, w4.w};
    uint16_t hh[4], mm[4];
#pragma unroll
    for (int j = 0; j < 4; ++j) {
        uint16_t a = f2bf(wv[j]);
        float r = wv[j] - bf2f(a);   // exact (Sterbenz)
        hh[j] = a; mm[j] = f2bf(r);
    }
    *(ushort4*)(Wh + i) = make_ushort4(hh[0], hh[1], hh[2], hh[3]);
    *(ushort4*)(Wm + i) = make_ushort4(mm[0], mm[1], mm[2], mm[3]);
}

// ---- Kernel 1 (fused): LIF1 -> LDS(bf16) + A8, GEMM(double bf16) + LIF2 ----
// Block: 512 threads (8 waves), owns 16 bn rows (64 GEMM rows) x FULL N=512.
//  Phase 1: fp32 LIF1 chain (bitwise == numpy), spikes to LDS as bf16
//           (XOR-swizzled rows) and to A8 global (bytes, for k_fix).
//  Phase 2: barrier-free K-loop; A from LDS, Wh/Wm from L2; 2 MFMAs/K-slice.
//  Phase 3: LIF2 spikes -> ballot -> 4KB LDS bitmask; barrier; fully
//           coalesced float4 gating pass (in outputs-half -> out).
//           (Round-1 postmortem: scattered 4B epilogue held the kernel at
//            1.39 TB/s; rows are now streamed as whole 2KB lines.)
#define DELTA 1e-3f
__global__ __launch_bounds__(512, 4) void k_fused(
        const float*    __restrict__ in,
        const uint16_t* __restrict__ Wh,
        const uint16_t* __restrict__ Wm,
        const float*    __restrict__ bias,
        float*          __restrict__ out,
        uint8_t*        __restrict__ A8,
        unsigned int*   __restrict__ counter,
        unsigned int*   __restrict__ list,
        unsigned int    cap) {
    __shared__ short A_lds[64 * 512];            // 64 KiB, row = bn_l*4 + t
    __shared__ unsigned short gate_bits[64 * 32]; // 4 KiB: [row][e/16] bitmask

    const int tid = threadIdx.x;
    const int blk = blockIdx.x;         // 1024 blocks
    const int bn0 = blk * 16;

    // ---------------- Phase 1: LIF1 (2 (bn,d-group) pairs per thread) -------
#pragma unroll
    for (int pp = 0; pp < 2; ++pp) {
        const int p   = tid + pp * 512;   // 0..1023 = 16 bn x 64 d-groups
        const int bnl = p >> 6;
        const int g   = p & 63;
        const int d0  = g << 3;
        const int bng = bn0 + bnl;
        float v[8] = {0.f,0.f,0.f,0.f,0.f,0.f,0.f,0.f};
#pragma unroll
        for (int t = 0; t < TS; ++t) {
            const float4* px = (const float4*)(in + ((size_t)(t * BNROWS + bng)) * CIN + DIMN + d0);
            float4 x0 = px[0], x1 = px[1];
            float xs[8] = {x0.x, x0.y, x0.z, x0.w, x1.x, x1.y, x1.z, x1.w};
            short8 sb;
            union { uint2 u; uint8_t b[8]; } pk;
#pragma unroll
            for (int j = 0; j < 8; ++j) {
                v[j] = v[j] * 0.5f + xs[j];      // charge (x0.5 exact)
                bool sp = (v[j] >= 1.0f);        // fire
                sb[j]   = sp ? (short)0x3F80 : (short)0;   // bf16 1.0/0.0
                pk.b[j] = sp ? 1u : 0u;
                v[j] = sp ? 0.0f : v[j];         // hard reset
            }
            const int row  = (bnl << 2) + t;
            const int boff = row * 1024 + ((d0 * 2) ^ ((row & 7) << 4));  // XOR swizzle
            *(short8*)((char*)A_lds + boff) = sb;
            *(uint2*)(A8 + ((size_t)((bng << 2) + t)) * DIMN + d0) = pk.u;
        }
    }
    __syncthreads();   // A_lds ready; read-only through phase 2

    // ---------------- Phase 2: GEMM (double bf16) ---------------------------
    const int wv   = tid >> 6;          // 8 waves -> e ranges of 64
    const int lane = tid & 63;
    const int ln   = lane & 15;
    const int quad = lane >> 4;
    const int e_base = wv * 64;

    f32x4 acc[4][4] = {};   // [mi][ni]

#pragma unroll 4
    for (int ks = 0; ks < 16; ++ks) {
        const int k0 = ks * 32 + quad * 8;
        short8 a[4];
#pragma unroll
        for (int mi = 0; mi < 4; ++mi) {
            const int row  = mi * 16 + ln;
            const int boff = row * 1024 + ((k0 * 2) ^ ((row & 7) << 4));
            a[mi] = *(const short8*)((const char*)A_lds + boff);
        }
#pragma unroll
        for (int ni = 0; ni < 4; ++ni) {
            const size_t off = (size_t)(e_base + ni * 16 + ln) * DIMN + k0;
            short8 bh = *(const short8*)(Wh + off);
            short8 bm = *(const short8*)(Wm + off);
#pragma unroll
            for (int mi = 0; mi < 4; ++mi) {
                acc[mi][ni] = __builtin_amdgcn_mfma_f32_16x16x32_bf16(a[mi], bh, acc[mi][ni], 0, 0, 0);
                acc[mi][ni] = __builtin_amdgcn_mfma_f32_16x16x32_bf16(a[mi], bm, acc[mi][ni], 0, 0, 0);
            }
        }
    }

    // ------------- Phase 3a: LIF2 + ballot spikes into LDS bitmask ----------
    // C/D layout 16x16: col = lane&15, row = quad*4 + reg. t = reg, bn = row/4.
#pragma unroll
    for (int ni = 0; ni < 4; ++ni) {
        const int e = e_base + ni * 16 + ln;
        const float be = bias[e];
#pragma unroll
        for (int mi = 0; mi < 4; ++mi) {
            const int bn = bn0 + mi * 4 + quad;
            float v = 0.f;
            bool bad = false;
#pragma unroll
            for (int t = 0; t < TS; ++t) {
                float y = acc[mi][ni][t] + be;      // Linear + bias
                v = v * 0.5f + y;                   // LIF2 charge
                bad = bad || (fabsf(v - 1.0f) < DELTA);
                bool sp = (v >= 1.0f);
                unsigned long long b = __ballot(sp);
                if (ln == 0) {
                    // bits [quad*16 .. quad*16+15] = e_base+ni*16 .. +15 for this quad's bn
                    const int row_l = (mi * 4 + quad) * 4 + t;
                    gate_bits[row_l * 32 + (wv * 4 + ni)] =
                        (unsigned short)((b >> (quad * 16)) & 0xFFFFull);
                }
                v = sp ? 0.0f : v;                  // hard reset
            }
            if (bad) {
                unsigned idx = atomicAdd(counter, 1u);
                if (idx < cap) list[idx] = ((unsigned)bn << 9) | (unsigned)e;
            }
        }
    }
    __syncthreads();   // gate_bits complete

    // ------------- Phase 3b: coalesced gating pass (float4 rows) ------------
    // 4 t x 16 bn x 512 e = 8192 float4 slots; 512 threads x 16 iters.
#pragma unroll
    for (int it = 0; it < 16; ++it) {
        const int s   = it * 512 + tid;   // consecutive tids -> contiguous c
        const int t   = s >> 11;          // 0..3
        const int bnl = (s >> 7) & 15;    // 0..15
        const int c   = s & 127;          // float4 index within 512-float row
        const size_t rbase = (size_t)(t * BNROWS + bn0 + bnl);
        const float4 ov = *(const float4*)(in + rbase * CIN + (c << 2));   // outputs half
        const unsigned gb = gate_bits[(bnl * 4 + t) * 32 + (c >> 2)];
        const int sh = (c & 3) * 4;
        float4 o;
        o.x = ((gb >> (sh + 0)) & 1u) ? ov.x : 0.0f;
        o.y = ((gb >> (sh + 1)) & 1u) ? ov.y : 0.0f;
        o.z = ((gb >> (sh + 2)) & 1u) ? ov.z : 0.0f;
        o.w = ((gb >> (sh + 3)) & 1u) ? ov.w : 0.0f;
        *(float4*)(out + rbase * DIMN + (c << 2)) = o;
    }
}

// ------- Kernel 3: bitwise emulation of numpy fp32 einsum + LIF2 ------------
__global__ __launch_bounds__(256) void k_fix(
        const uint8_t* __restrict__ A8,
        const float*   __restrict__ W,
        const float*   __restrict__ bias,
        const float*   __restrict__ in,
        float*         __restrict__ out,
        const unsigned int* __restrict__ counter,
        const unsigned int* __restrict__ list,
        unsigned int cap) {
    unsigned n = *counter; if (n > cap) n = cap;
    unsigned gtid = blockIdx.x * blockDim.x + threadIdx.x;
    unsigned gsz  = gridDim.x * blockDim.x;
    for (unsigned i = gtid; i < n; i += gsz) {
        unsigned item = list[i];
        int bn = (int)(item >> 9), e = (int)(item & 511u);
        const float* wrow = W + (size_t)e * DIMN;
        float v = 0.f;
        for (int t = 0; t < TS; ++t) {
            const uint8_t* arow = A8 + (size_t)(bn * 4 + t) * DIMN;
            float acc0 = 0.f, acc1 = 0.f, acc2 = 0.f, acc3 = 0.f;
            for (int c = 0; c < 32; ++c) {          // 32 blocks of 16
                const int base = c * 16;
#pragma unroll
                for (int j = 3; j >= 0; --j) {      // chained: j=3,2,1,0
                    const int b4 = base + j * 4;
                    float s0 = arow[b4 + 0] ? 1.0f : 0.0f;
                    float s1 = arow[b4 + 1] ? 1.0f : 0.0f;
                    float s2 = arow[b4 + 2] ? 1.0f : 0.0f;
                    float s3 = arow[b4 + 3] ? 1.0f : 0.0f;
                    acc0 = fmaf(s0, wrow[b4 + 0], acc0);
                    acc1 = fmaf(s1, wrow[b4 + 1], acc1);
                    acc2 = fmaf(s2, wrow[b4 + 2], acc2);
                    acc3 = fmaf(s3, wrow[b4 + 3], acc3);
                }
            }
            float lo  = acc0 + acc1;                // SSE3 hadd reduce
            float hi  = acc2 + acc3;
            float dot = lo + hi;
            float y = dot + bias[e];
            v = v * 0.5f + y;                        // fp32 chain, x0.5 exact
            bool sp = (v >= 1.0f);
            size_t obase = (size_t)(t * BNROWS + bn);
            out[obase * DIMN + e] = sp ? in[obase * CIN + e] : 0.0f;
            v = sp ? 0.0f : v;
        }
    }
}

extern "C" void kernel_launch(void* const* d_in, const int* in_sizes, int n_in,
                              void* d_out, int out_size, void* d_ws, size_t ws_size,
                              hipStream_t stream) {
    const float* in   = (const float*)d_in[0];   // [4,32,512,1024]
    const float* W    = (const float*)d_in[1];   // [512,512]
    const float* bias = (const float*)d_in[2];   // [512]
    float* out = (float*)d_out;                  // [4,32,512,512]

    // ws layout (total ~39 MB):
    // A8 int8 [65536][512] = 32 MB | Wh 512K | Wm 512K | counter 64B | list 4MB
    uint8_t*  A8 = (uint8_t*)d_ws;
    uint16_t* Wh = (uint16_t*)((char*)d_ws + (size_t)33554432);
    uint16_t* Wm = (uint16_t*)((char*)d_ws + (size_t)34078720);
    unsigned int* counter = (unsigned int*)((char*)d_ws + (size_t)34603008);
    unsigned int* list    = (unsigned int*)((char*)d_ws + (size_t)34603072);
    const unsigned int cap = 1000000u;

    hipMemsetAsync(counter, 0, sizeof(unsigned int), stream);
    k_wsplit<<<256, 256, 0, stream>>>(W, Wh, Wm);
    k_fused<<<1024, 512, 0, stream>>>(in, Wh, Wm, bias, out, A8, counter, list, cap);
    k_fix<<<256, 256, 0, stream>>>(A8, W, bias, in, out, counter, list, cap);
}

// Round 3
// 606.307 us; speedup vs baseline: 1.1519x; 1.1519x over previous
//
#include <hip/hip_runtime.h>
#include <cstdint>
#include <cstddef>

// Problem constants
#define TS     4
#define BNROWS 16384   // B*N = 32*512
#define DIMN   512
#define CIN    1024    // 2*DIM

typedef __attribute__((ext_vector_type(8))) short short8;   // 8 bf16
typedef __attribute__((ext_vector_type(4))) float f32x4;

__device__ __forceinline__ uint16_t f2bf(float f) {
    union { float f; uint32_t u; } x; x.f = f;
    return (uint16_t)((x.u + 0x7FFFu + ((x.u >> 16) & 1u)) >> 16);  // RNE
}
__device__ __forceinline__ float bf2f(uint16_t h) {
    union { uint32_t u; float f; } x; x.u = ((uint32_t)h) << 16;
    return x.f;
}

// -------- Kernel 0: split W (fp32) into bf16 hi/mid, FRAGMENT-MAJOR --------
// Layout: Wt[ks][e][kk]  (ks = k>>5, kk = k&31), elements = ((ks*512+e)<<5)+kk.
// A wave's per-(ks,ni) MFMA B-fragment load then covers one contiguous,
// aligned 1 KB block (16 e-rows x 32 k x 2B) -> fully coalesced L2 reads.
// (Round-2 postmortem: row-major W gave 64-line/instr gathers; k_fused was
//  issue-serialized at ~8% MFMA/VALU with nothing saturated.)
__global__ __launch_bounds__(256) void k_wsplit(const float* __restrict__ W,
        uint16_t* __restrict__ Wh, uint16_t* __restrict__ Wm) {
    int i = (blockIdx.x * 256 + threadIdx.x) * 4;   // element idx in row-major W
    int e  = i >> 9;
    int k  = i & 511;
    int ks = k >> 5, kk = k & 31;
    size_t o = ((size_t)((ks << 9) + e) << 5) + kk;   // 4 consecutive kk's
    float4 w4 = *(const float4*)(W + i);
    float wv[4] = {w4.x, w4.y, w4.z, w4.w};
    uint16_t hh[4], mm[4];
#pragma unroll
    for (int j = 0; j < 4; ++j) {
        uint16_t a = f2bf(wv[j]);
        float r = wv[j] - bf2f(a);   // exact (Sterbenz)
        hh[j] = a; mm[j] = f2bf(r);
    }
    *(ushort4*)(Wh + o) = make_ushort4(hh[0], hh[1], hh[2], hh[3]);
    *(ushort4*)(Wm + o) = make_ushort4(mm[0], mm[1], mm[2], mm[3]);
}

// ---- Kernel 1 (fused): LIF1 -> LDS(bf16) + A8, GEMM(double bf16) + LIF2 ----
// Block: 512 threads (8 waves), owns 16 bn rows (64 GEMM rows) x FULL N=512.
//  Phase 1: fp32 LIF1 chain (bitwise == numpy), spikes to LDS as bf16
//           (XOR-swizzled rows) and to A8 global (bytes, for k_fix).
//  Phase 2: barrier-free K-loop; A from LDS, Wh/Wm fragment-major from L2
//           (contiguous 1KB per load); all 8 W loads grouped at loop top.
//  Phase 3: LIF2 spikes -> ballot -> 4KB LDS bitmask; barrier; fully
//           coalesced float4 gating pass (in outputs-half -> out).
#define DELTA 1e-3f
__global__ __launch_bounds__(512, 4) void k_fused(
        const float*    __restrict__ in,
        const uint16_t* __restrict__ Wh,
        const uint16_t* __restrict__ Wm,
        const float*    __restrict__ bias,
        float*          __restrict__ out,
        uint8_t*        __restrict__ A8,
        unsigned int*   __restrict__ counter,
        unsigned int*   __restrict__ list,
        unsigned int    cap) {
    __shared__ short A_lds[64 * 512];            // 64 KiB, row = bn_l*4 + t
    __shared__ unsigned short gate_bits[64 * 32]; // 4 KiB: [row][e/16] bitmask

    const int tid = threadIdx.x;
    const int blk = blockIdx.x;         // 1024 blocks
    const int bn0 = blk * 16;

    // ---------------- Phase 1: LIF1 (2 (bn,d-group) pairs per thread) -------
#pragma unroll
    for (int pp = 0; pp < 2; ++pp) {
        const int p   = tid + pp * 512;   // 0..1023 = 16 bn x 64 d-groups
        const int bnl = p >> 6;
        const int g   = p & 63;
        const int d0  = g << 3;
        const int bng = bn0 + bnl;
        float v[8] = {0.f,0.f,0.f,0.f,0.f,0.f,0.f,0.f};
#pragma unroll
        for (int t = 0; t < TS; ++t) {
            const float4* px = (const float4*)(in + ((size_t)(t * BNROWS + bng)) * CIN + DIMN + d0);
            float4 x0 = px[0], x1 = px[1];
            float xs[8] = {x0.x, x0.y, x0.z, x0.w, x1.x, x1.y, x1.z, x1.w};
            short8 sb;
            union { uint2 u; uint8_t b[8]; } pk;
#pragma unroll
            for (int j = 0; j < 8; ++j) {
                v[j] = v[j] * 0.5f + xs[j];      // charge (x0.5 exact)
                bool sp = (v[j] >= 1.0f);        // fire
                sb[j]   = sp ? (short)0x3F80 : (short)0;   // bf16 1.0/0.0
                pk.b[j] = sp ? 1u : 0u;
                v[j] = sp ? 0.0f : v[j];         // hard reset
            }
            const int row  = (bnl << 2) + t;
            const int boff = row * 1024 + ((d0 * 2) ^ ((row & 7) << 4));  // XOR swizzle
            *(short8*)((char*)A_lds + boff) = sb;
            *(uint2*)(A8 + ((size_t)((bng << 2) + t)) * DIMN + d0) = pk.u;
        }
    }
    __syncthreads();   // A_lds ready; read-only through phase 2

    // ---------------- Phase 2: GEMM (double bf16) ---------------------------
    const int wv   = tid >> 6;          // 8 waves -> e ranges of 64
    const int lane = tid & 63;
    const int ln   = lane & 15;
    const int quad = lane >> 4;
    const int e_base = wv * 64;

    f32x4 acc[4][4] = {};   // [mi][ni]

#pragma unroll 4
    for (int ks = 0; ks < 16; ++ks) {
        // ---- all global W loads first (coalesced 1KB blocks, hoistable) ----
        short8 bh[4], bm[4];
#pragma unroll
        for (int ni = 0; ni < 4; ++ni) {
            const size_t off = ((size_t)((ks << 9) + e_base + ni * 16 + ln) << 5) + quad * 8;
            bh[ni] = *(const short8*)(Wh + off);
            bm[ni] = *(const short8*)(Wm + off);
        }
        // ---- A fragments from LDS ----
        const int k0 = ks * 32 + quad * 8;
        short8 a[4];
#pragma unroll
        for (int mi = 0; mi < 4; ++mi) {
            const int row  = mi * 16 + ln;
            const int boff = row * 1024 + ((k0 * 2) ^ ((row & 7) << 4));
            a[mi] = *(const short8*)((const char*)A_lds + boff);
        }
        // ---- MFMAs ----
#pragma unroll
        for (int ni = 0; ni < 4; ++ni) {
#pragma unroll
            for (int mi = 0; mi < 4; ++mi) {
                acc[mi][ni] = __builtin_amdgcn_mfma_f32_16x16x32_bf16(a[mi], bh[ni], acc[mi][ni], 0, 0, 0);
                acc[mi][ni] = __builtin_amdgcn_mfma_f32_16x16x32_bf16(a[mi], bm[ni], acc[mi][ni], 0, 0, 0);
            }
        }
    }

    // ------------- Phase 3a: LIF2 + ballot spikes into LDS bitmask ----------
    // C/D layout 16x16: col = lane&15, row = quad*4 + reg. t = reg, bn = row/4.
#pragma unroll
    for (int ni = 0; ni < 4; ++ni) {
        const int e = e_base + ni * 16 + ln;
        const float be = bias[e];
#pragma unroll
        for (int mi = 0; mi < 4; ++mi) {
            const int bn = bn0 + mi * 4 + quad;
            float v = 0.f;
            bool bad = false;
#pragma unroll
            for (int t = 0; t < TS; ++t) {
                float y = acc[mi][ni][t] + be;      // Linear + bias
                v = v * 0.5f + y;                   // LIF2 charge
                bad = bad || (fabsf(v - 1.0f) < DELTA);
                bool sp = (v >= 1.0f);
                unsigned long long b = __ballot(sp);
                if (ln == 0) {
                    const int row_l = (mi * 4 + quad) * 4 + t;
                    gate_bits[row_l * 32 + (wv * 4 + ni)] =
                        (unsigned short)((b >> (quad * 16)) & 0xFFFFull);
                }
                v = sp ? 0.0f : v;                  // hard reset
            }
            if (bad) {
                unsigned idx = atomicAdd(counter, 1u);
                if (idx < cap) list[idx] = ((unsigned)bn << 9) | (unsigned)e;
            }
        }
    }
    __syncthreads();   // gate_bits complete

    // ------------- Phase 3b: coalesced gating pass (float4 rows) ------------
#pragma unroll
    for (int it = 0; it < 16; ++it) {
        const int s   = it * 512 + tid;   // consecutive tids -> contiguous c
        const int t   = s >> 11;          // 0..3
        const int bnl = (s >> 7) & 15;    // 0..15
        const int c   = s & 127;          // float4 index within 512-float row
        const size_t rbase = (size_t)(t * BNROWS + bn0 + bnl);
        const float4 ov = *(const float4*)(in + rbase * CIN + (c << 2));   // outputs half
        const unsigned gb = gate_bits[(bnl * 4 + t) * 32 + (c >> 2)];
        const int sh = (c & 3) * 4;
        float4 o;
        o.x = ((gb >> (sh + 0)) & 1u) ? ov.x : 0.0f;
        o.y = ((gb >> (sh + 1)) & 1u) ? ov.y : 0.0f;
        o.z = ((gb >> (sh + 2)) & 1u) ? ov.z : 0.0f;
        o.w = ((gb >> (sh + 3)) & 1u) ? ov.w : 0.0f;
        *(float4*)(out + rbase * DIMN + (c << 2)) = o;
    }
}

// ------- Kernel 3: bitwise emulation of numpy fp32 einsum + LIF2 ------------
// (uses the ORIGINAL row-major fp32 W -> unaffected by the Wt layout change)
__global__ __launch_bounds__(256) void k_fix(
        const uint8_t* __restrict__ A8,
        const float*   __restrict__ W,
        const float*   __restrict__ bias,
        const float*   __restrict__ in,
        float*         __restrict__ out,
        const unsigned int* __restrict__ counter,
        const unsigned int* __restrict__ list,
        unsigned int cap) {
    unsigned n = *counter; if (n > cap) n = cap;
    unsigned gtid = blockIdx.x * blockDim.x + threadIdx.x;
    unsigned gsz  = gridDim.x * blockDim.x;
    for (unsigned i = gtid; i < n; i += gsz) {
        unsigned item = list[i];
        int bn = (int)(item >> 9), e = (int)(item & 511u);
        const float* wrow = W + (size_t)e * DIMN;
        float v = 0.f;
        for (int t = 0; t < TS; ++t) {
            const uint8_t* arow = A8 + (size_t)(bn * 4 + t) * DIMN;
            float acc0 = 0.f, acc1 = 0.f, acc2 = 0.f, acc3 = 0.f;
            for (int c = 0; c < 32; ++c) {          // 32 blocks of 16
                const int base = c * 16;
#pragma unroll
                for (int j = 3; j >= 0; --j) {      // chained: j=3,2,1,0
                    const int b4 = base + j * 4;
                    float s0 = arow[b4 + 0] ? 1.0f : 0.0f;
                    float s1 = arow[b4 + 1] ? 1.0f : 0.0f;
                    float s2 = arow[b4 + 2] ? 1.0f : 0.0f;
                    float s3 = arow[b4 + 3] ? 1.0f : 0.0f;
                    acc0 = fmaf(s0, wrow[b4 + 0], acc0);
                    acc1 = fmaf(s1, wrow[b4 + 1], acc1);
                    acc2 = fmaf(s2, wrow[b4 + 2], acc2);
                    acc3 = fmaf(s3, wrow[b4 + 3], acc3);
                }
            }
            float lo  = acc0 + acc1;                // SSE3 hadd reduce
            float hi  = acc2 + acc3;
            float dot = lo + hi;
            float y = dot + bias[e];
            v = v * 0.5f + y;                        // fp32 chain, x0.5 exact
            bool sp = (v >= 1.0f);
            size_t obase = (size_t)(t * BNROWS + bn);
            out[obase * DIMN + e] = sp ? in[obase * CIN + e] : 0.0f;
            v = sp ? 0.0f : v;
        }
    }
}

extern "C" void kernel_launch(void* const* d_in, const int* in_sizes, int n_in,
                              void* d_out, int out_size, void* d_ws, size_t ws_size,
                              hipStream_t stream) {
    const float* in   = (const float*)d_in[0];   // [4,32,512,1024]
    const float* W    = (const float*)d_in[1];   // [512,512]
    const float* bias = (const float*)d_in[2];   // [512]
    float* out = (float*)d_out;                  // [4,32,512,512]

    // ws layout (total ~39 MB):
    // A8 int8 [65536][512] = 32 MB | Wh 512K | Wm 512K | counter 64B | list 4MB
    uint8_t*  A8 = (uint8_t*)d_ws;
    uint16_t* Wh = (uint16_t*)((char*)d_ws + (size_t)33554432);
    uint16_t* Wm = (uint16_t*)((char*)d_ws + (size_t)34078720);
    unsigned int* counter = (unsigned int*)((char*)d_ws + (size_t)34603008);
    unsigned int* list    = (unsigned int*)((char*)d_ws + (size_t)34603072);
    const unsigned int cap = 1000000u;

    hipMemsetAsync(counter, 0, sizeof(unsigned int), stream);
    k_wsplit<<<256, 256, 0, stream>>>(W, Wh, Wm);
    k_fused<<<1024, 512, 0, stream>>>(in, Wh, Wm, bias, out, A8, counter, list, cap);
    k_fix<<<256, 256, 0, stream>>>(A8, W, bias, in, out, counter, list, cap);
}